// Round 1
// baseline (166.350 us; speedup 1.0000x reference)
//
#include <hip/hip_runtime.h>
#include <math.h>

namespace {

constexpr int kN   = 512;   // nodes
constexpr int kFin = 64;    // in features
constexpr int kH   = 8;     // heads
constexpr int kFp  = 8;     // per-head out features
constexpr int kBT  = 96;    // B*T
constexpr int kNT  = 256;   // threads per block
constexpr float kNeg = 0.01f;
constexpr float kL2E = 1.44269504088896340736f;  // log2(e)

__device__ __forceinline__ float fast_exp2(float v) {
#if __has_builtin(__builtin_amdgcn_exp2f)
  return __builtin_amdgcn_exp2f(v);
#else
  return exp2f(v);
#endif
}

// Pack adj (512x512 fp32, values exactly 0/1) into bitmask bits[i][w] (w = j/32).
__global__ void pack_adj_kernel(const float* __restrict__ adj,
                                unsigned int* __restrict__ bits) {
  const int t = blockIdx.x * blockDim.x + threadIdx.x;  // [0, 512*16)
  const int i = t >> 4;
  const int w = t & 15;
  const float* row = adj + (size_t)i * kN + w * 32;
  unsigned int m = 0u;
#pragma unroll
  for (int k = 0; k < 32; ++k) m |= (row[k] != 0.0f) ? (1u << k) : 0u;
  bits[t] = m;
}

// One block per (bt, h) tile. Phase 1: h-tile + attention logit vectors.
// Phase 2: dense masked softmax + PV, 2 rows per thread.
__global__ __launch_bounds__(kNT) void gat_fused_kernel(
    const float* __restrict__ x, const unsigned int* __restrict__ bits,
    const float* __restrict__ W, const float* __restrict__ Wb,
    const float* __restrict__ a1, const float* __restrict__ a2,
    const float* __restrict__ ab, float* __restrict__ out) {
  __shared__ float4 h4[kN * 2];   // h-tile: per row j, two float4 (8 features)
  __shared__ float ssrc[kN];      // log2e * (a1 . h_j)

  const int bt  = blockIdx.x >> 3;
  const int h   = blockIdx.x & 7;
  const int tid = threadIdx.x;

  const float* xb = x + (size_t)bt * kN * kFin;
  const float* Wl = W + h * kFin * kFp;  // [64][8], wave-uniform -> s_load

  // ---------------- Phase 1: h = x @ W_h + b_h for rows tid, tid+256 --------
  float acc0[kFp], acc1[kFp];
#pragma unroll
  for (int f = 0; f < kFp; ++f) {
    const float b = Wb[h * kFp + f];
    acc0[f] = b;
    acc1[f] = b;
  }

  float xr0[kFin], xr1[kFin];
  const float4* p0 = reinterpret_cast<const float4*>(xb + (size_t)tid * kFin);
  const float4* p1 = reinterpret_cast<const float4*>(xb + (size_t)(tid + kNT) * kFin);
#pragma unroll
  for (int c = 0; c < kFin / 4; ++c) {
    *reinterpret_cast<float4*>(&xr0[c * 4]) = p0[c];
    *reinterpret_cast<float4*>(&xr1[c * 4]) = p1[c];
  }
#pragma unroll
  for (int i = 0; i < kFin; ++i) {
#pragma unroll
    for (int f = 0; f < kFp; ++f) {
      const float wv = Wl[i * kFp + f];  // scalar (SGPR) operand
      acc0[f] = fmaf(xr0[i], wv, acc0[f]);
      acc1[f] = fmaf(xr1[i], wv, acc1[f]);
    }
  }

  // attention logit pieces; fold log2(e) and ab into them
  float s1a = 0.f, s2a = 0.f, s1b = 0.f, s2b = 0.f;
#pragma unroll
  for (int f = 0; f < kFp; ++f) {
    const float A1 = a1[h * kFp + f];
    const float A2 = a2[h * kFp + f];
    s1a = fmaf(acc0[f], A1, s1a);
    s2a = fmaf(acc0[f], A2, s2a);
    s1b = fmaf(acc1[f], A1, s1b);
    s2b = fmaf(acc1[f], A2, s2b);
  }
  const float abh = ab[h];
  ssrc[tid]       = s1a * kL2E;
  ssrc[tid + kNT] = s1b * kL2E;
  const float sd0 = (s2a + abh) * kL2E;
  const float sd1 = (s2b + abh) * kL2E;

  h4[2 * tid]             = make_float4(acc0[0], acc0[1], acc0[2], acc0[3]);
  h4[2 * tid + 1]         = make_float4(acc0[4], acc0[5], acc0[6], acc0[7]);
  h4[2 * (tid + kNT)]     = make_float4(acc1[0], acc1[1], acc1[2], acc1[3]);
  h4[2 * (tid + kNT) + 1] = make_float4(acc1[4], acc1[5], acc1[6], acc1[7]);
  __syncthreads();

  // ---------------- Phase 2: masked softmax + PV over j ---------------------
  float o0[kFp], o1[kFp];
#pragma unroll
  for (int f = 0; f < kFp; ++f) {
    o0[f] = 0.f;
    o1[f] = 0.f;
  }
  float sum0 = 0.f, sum1 = 0.f;

  const unsigned int* brow0 = bits + tid * 16;
  const unsigned int* brow1 = bits + (tid + kNT) * 16;

#pragma unroll 1
  for (int w = 0; w < 16; ++w) {
    const unsigned int m0 = brow0[w];
    const unsigned int m1 = brow1[w];
#pragma unroll
    for (int jj = 0; jj < 32; ++jj) {
      const int j = w * 32 + jj;
      const float4 ha = h4[2 * j];      // wave-uniform LDS broadcast
      const float4 hb = h4[2 * j + 1];
      const float sj = ssrc[j];

      float e0 = sj + sd0;
      e0 = fmaxf(e0, kNeg * e0);        // leaky-relu (scale-invariant)
      if (!(m0 & (1u << jj))) e0 = -INFINITY;
      float e1 = sj + sd1;
      e1 = fmaxf(e1, kNeg * e1);
      if (!(m1 & (1u << jj))) e1 = -INFINITY;

      const float pv0 = fast_exp2(e0);  // exp(e) since log2e pre-folded
      const float pv1 = fast_exp2(e1);
      sum0 += pv0;
      sum1 += pv1;

      o0[0] = fmaf(pv0, ha.x, o0[0]);
      o0[1] = fmaf(pv0, ha.y, o0[1]);
      o0[2] = fmaf(pv0, ha.z, o0[2]);
      o0[3] = fmaf(pv0, ha.w, o0[3]);
      o0[4] = fmaf(pv0, hb.x, o0[4]);
      o0[5] = fmaf(pv0, hb.y, o0[5]);
      o0[6] = fmaf(pv0, hb.z, o0[6]);
      o0[7] = fmaf(pv0, hb.w, o0[7]);
      o1[0] = fmaf(pv1, ha.x, o1[0]);
      o1[1] = fmaf(pv1, ha.y, o1[1]);
      o1[2] = fmaf(pv1, ha.z, o1[2]);
      o1[3] = fmaf(pv1, ha.w, o1[3]);
      o1[4] = fmaf(pv1, hb.x, o1[4]);
      o1[5] = fmaf(pv1, hb.y, o1[5]);
      o1[6] = fmaf(pv1, hb.z, o1[6]);
      o1[7] = fmaf(pv1, hb.w, o1[7]);
    }
  }

  // ---------------- Epilogue: normalize + head-concat store -----------------
  const float r0 = 1.0f / sum0;
  const float r1 = 1.0f / sum1;
  float4* q0 = reinterpret_cast<float4*>(
      out + (((size_t)bt * kN + tid) * kH + h) * kFp);
  float4* q1 = reinterpret_cast<float4*>(
      out + (((size_t)bt * kN + tid + kNT) * kH + h) * kFp);
  q0[0] = make_float4(o0[0] * r0, o0[1] * r0, o0[2] * r0, o0[3] * r0);
  q0[1] = make_float4(o0[4] * r0, o0[5] * r0, o0[6] * r0, o0[7] * r0);
  q1[0] = make_float4(o1[0] * r1, o1[1] * r1, o1[2] * r1, o1[3] * r1);
  q1[1] = make_float4(o1[4] * r1, o1[5] * r1, o1[6] * r1, o1[7] * r1);
}

}  // namespace

extern "C" void kernel_launch(void* const* d_in, const int* in_sizes, int n_in,
                              void* d_out, int out_size, void* d_ws, size_t ws_size,
                              hipStream_t stream) {
  const float* x   = (const float*)d_in[0];
  const float* adj = (const float*)d_in[1];
  const float* W   = (const float*)d_in[2];
  const float* Wb  = (const float*)d_in[3];
  const float* a1  = (const float*)d_in[4];
  const float* a2  = (const float*)d_in[5];
  const float* ab  = (const float*)d_in[6];
  float* out = (float*)d_out;
  unsigned int* bits = (unsigned int*)d_ws;  // 512*16 u32 = 32 KB

  hipLaunchKernelGGL(pack_adj_kernel, dim3(kN * 16 / kNT), dim3(kNT), 0, stream,
                     adj, bits);
  hipLaunchKernelGGL(gat_fused_kernel, dim3(kBT * kH), dim3(kNT), 0, stream,
                     x, bits, W, Wb, a1, a2, ab, out);
}

// Round 3
// 141.273 us; speedup vs baseline: 1.1775x; 1.1775x over previous
//
#include <hip/hip_runtime.h>
#include <math.h>

namespace {

constexpr int kN   = 512;
constexpr int kFin = 64;
constexpr int kH   = 8;
constexpr int kFp  = 8;
constexpr int kBT  = 96;
constexpr int kNT  = 256;
constexpr float kNeg = 0.01f;
constexpr float kL2E = 1.44269504088896340736f;  // log2(e)

typedef __fp16 fp16x2 __attribute__((ext_vector_type(2)));
typedef _Float16 half8t __attribute__((ext_vector_type(8)));
typedef float f32x4 __attribute__((ext_vector_type(4)));
typedef unsigned int uint;

__device__ __forceinline__ float fast_exp2(float v) {
#if __has_builtin(__builtin_amdgcn_exp2f)
  return __builtin_amdgcn_exp2f(v);
#else
  return exp2f(v);
#endif
}

// 0 or 0xFFFFFFFF from bit b of w
__device__ __forceinline__ uint bit_smear(uint w, int b) {
  return (uint)(((int)(w << (31 - b))) >> 31);
}

// Coalesced adjacency pack: bit jj of bitsT[w][i] = (adj[i][w*32+jj] != 0).
// Transposed layout so the GAT kernel's per-row mask-word reads are
// 16-consecutive-word (conflict-free, broadcast across lane groups).
__global__ void pack_adj_kernel(const float* __restrict__ adj,
                                uint* __restrict__ bitsT) {
  const int t = blockIdx.x * blockDim.x + threadIdx.x;  // [0, 512*512)
  const float v = adj[t];
  const unsigned long long m = __ballot(v != 0.0f);
  const int lane = threadIdx.x & 63;
  if ((lane & 31) == 0) {
    const int i = t >> 9;           // row
    const int w = (t & 511) >> 5;   // word index 0..15
    bitsT[w * kN + i] = (uint)(m >> (lane & 32));
  }
}

// One block per (bt, h). Phase 1: h-tile + logit vectors (VALU, W via s_loads).
// Phase 2: P = exp2(masked lrelu(ssrc[j]+sdst[i])) built in registers as MFMA
// A-fragments; O = P @ [H | ones] via v_mfma_f32_16x16x32_f16 (col 8 = denom).
__global__ __launch_bounds__(kNT) void gat_mfma_kernel(
    const float* __restrict__ x, const uint* __restrict__ bitsT,
    const float* __restrict__ W, const float* __restrict__ Wb,
    const float* __restrict__ a1, const float* __restrict__ a2,
    const float* __restrict__ ab, float* __restrict__ out) {
  __shared__ _Float16 BfragS[16 * 64 * 8];  // [ks][lane][elem] f16, 16 KB
  __shared__ float ssrcS[kN];               // log2e * (a1.h_j)
  __shared__ float sdstS[kN];               // log2e * (a2.h_i + ab)
  __shared__ uint bitsS[16 * kN];           // bitsT staged, 32 KB

  const int bt  = blockIdx.x >> 3;
  const int h   = blockIdx.x & 7;
  const int tid = threadIdx.x;

  const float* xb = x + (size_t)bt * kN * kFin;
  const float* Wl = W + h * kFin * kFp;  // wave-uniform -> s_loads

  // Issue x row loads early (latency hides under LDS init/staging).
  float xr0[kFin], xr1[kFin];
  {
    const float4* p0 = reinterpret_cast<const float4*>(xb + (size_t)tid * kFin);
    const float4* p1 =
        reinterpret_cast<const float4*>(xb + (size_t)(tid + kNT) * kFin);
#pragma unroll
    for (int c4 = 0; c4 < kFin / 4; ++c4) {
      *reinterpret_cast<float4*>(&xr0[c4 * 4]) = p0[c4];
      *reinterpret_cast<float4*>(&xr1[c4 * 4]) = p1[c4];
    }
  }

  // Zero Bfrag (covers unused cols 9..15) and stage adjacency bits.
  {
    uint* bz = reinterpret_cast<uint*>(BfragS);
#pragma unroll
    for (int k2 = 0; k2 < 16; ++k2) bz[tid + kNT * k2] = 0u;
    uint4* bs4 = reinterpret_cast<uint4*>(bitsS);
    const uint4* gb4 = reinterpret_cast<const uint4*>(bitsT);
#pragma unroll
    for (int k2 = 0; k2 < 8; ++k2) bs4[tid + kNT * k2] = gb4[tid + kNT * k2];
  }
  __syncthreads();

  // ---------------- Phase 1: h = x @ W_h + b_h (rows tid, tid+256) ----------
  float acc0[kFp], acc1[kFp];
#pragma unroll
  for (int f = 0; f < kFp; ++f) {
    const float b = Wb[h * kFp + f];
    acc0[f] = b;
    acc1[f] = b;
  }
#pragma unroll
  for (int i = 0; i < kFin; ++i) {
#pragma unroll
    for (int f = 0; f < kFp; ++f) {
      const float wv = Wl[i * kFp + f];
      acc0[f] = fmaf(xr0[i], wv, acc0[f]);
      acc1[f] = fmaf(xr1[i], wv, acc1[f]);
    }
  }

  float s1a = 0.f, s2a = 0.f, s1b = 0.f, s2b = 0.f;
#pragma unroll
  for (int f = 0; f < kFp; ++f) {
    const float A1 = a1[h * kFp + f];
    const float A2 = a2[h * kFp + f];
    s1a = fmaf(acc0[f], A1, s1a);
    s2a = fmaf(acc0[f], A2, s2a);
    s1b = fmaf(acc1[f], A1, s1b);
    s2b = fmaf(acc1[f], A2, s2b);
  }
  const float abh = ab[h];
  ssrcS[tid]       = s1a * kL2E;
  ssrcS[tid + kNT] = s1b * kL2E;
  sdstS[tid]       = (s2a + abh) * kL2E;
  sdstS[tid + kNT] = (s2b + abh) * kL2E;

  // Scatter h rows into MFMA B-fragment layout (f16), plus ones column n=8.
  // elem index = ks*512 + (g*16+n)*8 + jj,  j = ks*32 + g*8 + jj.
  {
    const int j = tid;
    const int base = (j >> 5) * 512 + ((j >> 3) & 3) * 128 + (j & 7);
#pragma unroll
    for (int n = 0; n < kFp; ++n) BfragS[base + n * 8] = (_Float16)acc0[n];
    BfragS[base + 64] = (_Float16)1.0f;
  }
  {
    const int j = tid + kNT;
    const int base = (j >> 5) * 512 + ((j >> 3) & 3) * 128 + (j & 7);
#pragma unroll
    for (int n = 0; n < kFp; ++n) BfragS[base + n * 8] = (_Float16)acc1[n];
    BfragS[base + 64] = (_Float16)1.0f;
  }
  __syncthreads();

  // ---------------- Phase 2: P @ [H | 1] via MFMA ---------------------------
  const int l  = tid & 63;
  const int wv = tid >> 6;   // wave id 0..3 -> rows wv*128 .. wv*128+127
  const int g  = l >> 4;     // k-group
  const int c  = l & 15;     // A row within tile / C col
  const int kb = g * 8;      // k offset within K-step

  float sdr[8];
#pragma unroll
  for (int it = 0; it < 8; ++it) sdr[it] = sdstS[wv * 128 + it * 16 + c];

  f32x4 acc[8];
#pragma unroll
  for (int it = 0; it < 8; ++it) acc[it] = (f32x4){0.f, 0.f, 0.f, 0.f};

  const float4* s4 = reinterpret_cast<const float4*>(ssrcS);
#pragma unroll 1
  for (int ks = 0; ks < 16; ++ks) {
    const half8t bf =
        *reinterpret_cast<const half8t*>(&BfragS[ks * 512 + l * 8]);
    const float4 sa = s4[ks * 8 + g * 2];      // ssrc[ks*32+kb .. +3]
    const float4 sb = s4[ks * 8 + g * 2 + 1];  // ssrc[ks*32+kb+4 .. +7]
    const float sv[8] = {sa.x, sa.y, sa.z, sa.w, sb.x, sb.y, sb.z, sb.w};
    const uint* brow = &bitsS[ks * kN + wv * 128];
#pragma unroll
    for (int it = 0; it < 8; ++it) {
      const uint mw = brow[it * 16 + c] >> kb;
      const float sd = sdr[it];
      float pv[8];
#pragma unroll
      for (int jj = 0; jj < 8; ++jj) {
        float e = sv[jj] + sd;
        e = fmaxf(e, e * kNeg);               // leaky-relu (scale-invariant)
        const float p = fast_exp2(e);         // exp(e), log2e pre-folded
        pv[jj] = __uint_as_float(__float_as_uint(p) & bit_smear(mw, jj));
      }
      union { half8t v; fp16x2 h2[4]; } A;
#pragma unroll
      for (int q = 0; q < 4; ++q)
        A.h2[q] = __builtin_amdgcn_cvt_pkrtz(pv[2 * q], pv[2 * q + 1]);
      acc[it] =
          __builtin_amdgcn_mfma_f32_16x16x32_f16(A.v, bf, acc[it], 0, 0, 0);
    }
  }

  // ---------------- Epilogue: normalize by col-8 denom, store ---------------
  // C layout: col = l&15, rows = g*4 + r. Denom for those rows lives in the
  // same group's col-8 lane.
  const int srcl = (l & 48) + 8;
#pragma unroll
  for (int it = 0; it < 8; ++it) {
    const f32x4 a = acc[it];
#pragma unroll
    for (int r = 0; r < 4; ++r) {
      const float dn = __shfl(a[r], srcl, 64);
      const float v = a[r] / dn;
      if (c < kFp) {
        const int i = wv * 128 + it * 16 + g * 4 + r;
        out[((size_t)bt * kN + i) * (kH * kFp) + h * kFp + c] = v;
      }
    }
  }
}

}  // namespace

extern "C" void kernel_launch(void* const* d_in, const int* in_sizes, int n_in,
                              void* d_out, int out_size, void* d_ws, size_t ws_size,
                              hipStream_t stream) {
  const float* x   = (const float*)d_in[0];
  const float* adj = (const float*)d_in[1];
  const float* W   = (const float*)d_in[2];
  const float* Wb  = (const float*)d_in[3];
  const float* a1  = (const float*)d_in[4];
  const float* a2  = (const float*)d_in[5];
  const float* ab  = (const float*)d_in[6];
  float* out = (float*)d_out;
  uint* bitsT = (uint*)d_ws;  // [16][512] u32 = 32 KB, transposed adjacency

  hipLaunchKernelGGL(pack_adj_kernel, dim3(kN * kN / kNT), dim3(kNT), 0, stream,
                     adj, bitsT);
  hipLaunchKernelGGL(gat_mfma_kernel, dim3(kBT * kH), dim3(kNT), 0, stream,
                     x, bitsT, W, Wb, a1, a2, ab, out);
}

// Round 4
// 128.996 us; speedup vs baseline: 1.2896x; 1.0952x over previous
//
#include <hip/hip_runtime.h>
#include <math.h>

namespace {

constexpr int kN    = 512;
constexpr int kFin  = 64;
constexpr int kH    = 8;
constexpr int kFp   = 8;
constexpr int kBT   = 96;
constexpr int kNT   = 256;
constexpr int kMaxDeg = 104;   // padded CSR slot count (mean deg ~27, 14-sigma safe)
constexpr float kNeg = 0.01f;
constexpr float kL2E = 1.44269504088896340736f;  // log2(e)

typedef _Float16 half8t __attribute__((ext_vector_type(8)));
typedef unsigned int uint;

__device__ __forceinline__ float fast_exp2(float v) {
#if __has_builtin(__builtin_amdgcn_exp2f)
  return __builtin_amdgcn_exp2f(v);
#else
  return exp2f(v);
#endif
}

// ---- ws layout (u32 words) ----
// bitsR : [512*16]          row-major adjacency bitmask
// permG : [512]             sorted_pos -> row id
// degG  : [512]             sorted_pos -> degree
// idxG  : [kMaxDeg*512]     slot-major padded CSR: idxG[slot*512 + pos] = j
constexpr int kOffBits = 0;
constexpr int kOffPerm = kOffBits + kN * 16;
constexpr int kOffDeg  = kOffPerm + kN;
constexpr int kOffIdx  = kOffDeg + kN;

// Coalesced pack: bit jj of bitsR[i*16+w] = (adj[i][w*32+jj] != 0).
__global__ void pack_adj_kernel(const float* __restrict__ adj,
                                uint* __restrict__ bitsR) {
  const int t = blockIdx.x * blockDim.x + threadIdx.x;  // [0, 512*512)
  const unsigned long long m = __ballot(adj[t] != 0.0f);
  const int lane = threadIdx.x & 63;
  if ((lane & 31) == 0) {
    const int i = t >> 9;
    const int w = (t & 511) >> 5;
    bitsR[i * 16 + w] = (uint)(m >> (lane & 32));
  }
}

// One block, 512 threads. Degree count -> LDS counting sort by degree ->
// slot-major padded CSR fill (coalesced reads for the GAT kernel).
__global__ __launch_bounds__(512) void csr_build_kernel(
    const uint* __restrict__ bitsR, uint* __restrict__ permG,
    uint* __restrict__ degG, uint* __restrict__ idxG) {
  __shared__ int base[128];
  const int i = threadIdx.x;

  uint b[16];
  int deg = 0;
#pragma unroll
  for (int w = 0; w < 16; ++w) {
    b[w] = bitsR[i * 16 + w];
    deg += __popc(b[w]);
  }
  const int dc = min(deg, 127);

  if (i < 128) base[i] = 0;
  __syncthreads();
  atomicAdd(&base[dc], 1);           // histogram
  __syncthreads();
  if (i == 0) {                      // exclusive prefix sum (serial, 128 bins)
    int run = 0;
    for (int k = 0; k < 128; ++k) {
      const int c = base[k];
      base[k] = run;
      run += c;
    }
  }
  __syncthreads();
  const int pos = atomicAdd(&base[dc], 1);  // allocation cursor
  permG[pos] = (uint)i;
  degG[pos] = (uint)deg;

  int slot = 0;
#pragma unroll 1
  for (int w = 0; w < 16; ++w) {
    uint m = b[w];
    while (m) {
      const int j = w * 32 + __builtin_ctz(m);
      m &= m - 1;
      if (slot < kMaxDeg) idxG[slot * kN + pos] = (uint)j;
      ++slot;
    }
  }
  for (; slot < kMaxDeg; ++slot) idxG[slot * kN + pos] = 0u;  // pad (q forced 0)
}

// One block per (bt, h). Phase 1: h-tile + logit vectors (f32 VALU, W via
// s_loads). Phase 2: sparse softmax+PV over padded sorted CSR; f32 P,
// f16 h gather (ds_read_b128), v_fma_mix accumulate.
__global__ __launch_bounds__(kNT) void gat_sparse_kernel(
    const float* __restrict__ x, const uint* __restrict__ permG,
    const uint* __restrict__ degG, const uint* __restrict__ idxG,
    const float* __restrict__ W, const float* __restrict__ Wb,
    const float* __restrict__ a1, const float* __restrict__ a2,
    const float* __restrict__ ab, float* __restrict__ out) {
  __shared__ _Float16 h16S[kN * 8];  // 8 KB: f16 h rows
  __shared__ float ssrcS[kN];        // log2e * (a1.h_j)
  __shared__ float sdstS[kN];        // log2e * (a2.h_i + ab)

  const int bt  = blockIdx.x >> 3;
  const int h   = blockIdx.x & 7;
  const int tid = threadIdx.x;

  const float* xb = x + (size_t)bt * kN * kFin;
  const float* Wl = W + h * kFin * kFp;  // wave-uniform -> s_loads

  // ---------------- Phase 1: h = x @ W_h + b_h (rows tid, tid+256) ----------
  float xr0[kFin], xr1[kFin];
  {
    const float4* p0 = reinterpret_cast<const float4*>(xb + (size_t)tid * kFin);
    const float4* p1 =
        reinterpret_cast<const float4*>(xb + (size_t)(tid + kNT) * kFin);
#pragma unroll
    for (int c4 = 0; c4 < kFin / 4; ++c4) {
      *reinterpret_cast<float4*>(&xr0[c4 * 4]) = p0[c4];
      *reinterpret_cast<float4*>(&xr1[c4 * 4]) = p1[c4];
    }
  }

  float acc0[kFp], acc1[kFp];
#pragma unroll
  for (int f = 0; f < kFp; ++f) {
    const float b = Wb[h * kFp + f];
    acc0[f] = b;
    acc1[f] = b;
  }
#pragma unroll
  for (int i = 0; i < kFin; ++i) {
#pragma unroll
    for (int f = 0; f < kFp; ++f) {
      const float wv = Wl[i * kFp + f];
      acc0[f] = fmaf(xr0[i], wv, acc0[f]);
      acc1[f] = fmaf(xr1[i], wv, acc1[f]);
    }
  }

  float s1a = 0.f, s2a = 0.f, s1b = 0.f, s2b = 0.f;
#pragma unroll
  for (int f = 0; f < kFp; ++f) {
    const float A1 = a1[h * kFp + f];
    const float A2 = a2[h * kFp + f];
    s1a = fmaf(acc0[f], A1, s1a);
    s2a = fmaf(acc0[f], A2, s2a);
    s1b = fmaf(acc1[f], A1, s1b);
    s2b = fmaf(acc1[f], A2, s2b);
  }
  const float abh = ab[h];
  ssrcS[tid]       = s1a * kL2E;
  ssrcS[tid + kNT] = s1b * kL2E;
  sdstS[tid]       = (s2a + abh) * kL2E;
  sdstS[tid + kNT] = (s2b + abh) * kL2E;

  {
    half8t hv;
#pragma unroll
    for (int f = 0; f < kFp; ++f) hv[f] = (_Float16)acc0[f];
    *reinterpret_cast<half8t*>(&h16S[(size_t)tid * 8]) = hv;
#pragma unroll
    for (int f = 0; f < kFp; ++f) hv[f] = (_Float16)acc1[f];
    *reinterpret_cast<half8t*>(&h16S[(size_t)(tid + kNT) * 8]) = hv;
  }
  __syncthreads();

  // ---------------- Phase 2: sparse masked softmax + PV ---------------------
  // Thread handles adjacent sorted positions 2t, 2t+1 (similar degree).
  const int p0 = 2 * tid;  // p1 = p0 + 1
  const uint2 ip = *reinterpret_cast<const uint2*>(&permG[p0]);
  const uint2 dp = *reinterpret_cast<const uint2*>(&degG[p0]);
  const int i0 = (int)ip.x, i1 = (int)ip.y;
  const int d0 = (int)dp.x, d1 = (int)dp.y;
  const float sd0 = sdstS[i0];
  const float sd1 = sdstS[i1];
  const int dmax = max(d0, d1);

  float o0[kFp], o1[kFp];
#pragma unroll
  for (int f = 0; f < kFp; ++f) {
    o0[f] = 0.f;
    o1[f] = 0.f;
  }
  float sum0 = 0.f, sum1 = 0.f;

  uint2 jj = *reinterpret_cast<const uint2*>(&idxG[p0]);  // slot 0
#pragma unroll 1
  for (int slot = 0; slot < dmax; ++slot) {
    const int sn = min(slot + 1, kMaxDeg - 1);  // prefetch next (always valid)
    const uint2 jn = *reinterpret_cast<const uint2*>(&idxG[sn * kN + p0]);

    const half8t hv0 =
        *reinterpret_cast<const half8t*>(&h16S[(size_t)jj.x * 8]);
    const half8t hv1 =
        *reinterpret_cast<const half8t*>(&h16S[(size_t)jj.y * 8]);
    float e0 = ssrcS[jj.x] + sd0;
    float e1 = ssrcS[jj.y] + sd1;
    e0 = fmaxf(e0, e0 * kNeg);  // leaky-relu (commutes with log2e scale)
    e1 = fmaxf(e1, e1 * kNeg);
    float q0 = fast_exp2(e0);
    float q1 = fast_exp2(e1);
    q0 = (slot < d0) ? q0 : 0.f;  // pad / shorter-row predication
    q1 = (slot < d1) ? q1 : 0.f;
    sum0 += q0;
    sum1 += q1;
#pragma unroll
    for (int f = 0; f < kFp; ++f) {
      o0[f] = fmaf((float)hv0[f], q0, o0[f]);  // v_fma_mix_f32
      o1[f] = fmaf((float)hv1[f], q1, o1[f]);
    }
    jj = jn;
  }

  // ---------------- Epilogue: normalize + head-concat store -----------------
  const float r0 = 1.0f / sum0;
  const float r1 = 1.0f / sum1;
  float* q0p = out + (((size_t)bt * kN + i0) * kH + h) * kFp;
  float* q1p = out + (((size_t)bt * kN + i1) * kH + h) * kFp;
  reinterpret_cast<float4*>(q0p)[0] =
      make_float4(o0[0] * r0, o0[1] * r0, o0[2] * r0, o0[3] * r0);
  reinterpret_cast<float4*>(q0p)[1] =
      make_float4(o0[4] * r0, o0[5] * r0, o0[6] * r0, o0[7] * r0);
  reinterpret_cast<float4*>(q1p)[0] =
      make_float4(o1[0] * r1, o1[1] * r1, o1[2] * r1, o1[3] * r1);
  reinterpret_cast<float4*>(q1p)[1] =
      make_float4(o1[4] * r1, o1[5] * r1, o1[6] * r1, o1[7] * r1);
}

}  // namespace

extern "C" void kernel_launch(void* const* d_in, const int* in_sizes, int n_in,
                              void* d_out, int out_size, void* d_ws, size_t ws_size,
                              hipStream_t stream) {
  const float* x   = (const float*)d_in[0];
  const float* adj = (const float*)d_in[1];
  const float* W   = (const float*)d_in[2];
  const float* Wb  = (const float*)d_in[3];
  const float* a1  = (const float*)d_in[4];
  const float* a2  = (const float*)d_in[5];
  const float* ab  = (const float*)d_in[6];
  float* out = (float*)d_out;

  uint* ws    = (uint*)d_ws;
  uint* bitsR = ws + kOffBits;
  uint* permG = ws + kOffPerm;
  uint* degG  = ws + kOffDeg;
  uint* idxG  = ws + kOffIdx;

  hipLaunchKernelGGL(pack_adj_kernel, dim3(kN * kN / kNT), dim3(kNT), 0, stream,
                     adj, bitsR);
  hipLaunchKernelGGL(csr_build_kernel, dim3(1), dim3(512), 0, stream,
                     bitsR, permG, degG, idxG);
  hipLaunchKernelGGL(gat_sparse_kernel, dim3(kBT * kH), dim3(kNT), 0, stream,
                     x, permG, degG, idxG, W, Wb, a1, a2, ab, out);
}

// Round 5
// 107.717 us; speedup vs baseline: 1.5443x; 1.1976x over previous
//
#include <hip/hip_runtime.h>
#include <math.h>

namespace {

constexpr int kN    = 512;
constexpr int kFin  = 64;
constexpr int kH    = 8;
constexpr int kFp   = 8;
constexpr int kBT   = 96;
constexpr int kNT   = 256;
constexpr int kMaxDeg = 104;   // idxG slot capacity (max row degree ~45)
constexpr float kNeg = 0.01f;
constexpr float kL2E = 1.44269504088896340736f;  // log2(e)

typedef _Float16 half8t __attribute__((ext_vector_type(8)));
typedef unsigned int uint;

__device__ __forceinline__ float fast_exp2(float v) {
#if __has_builtin(__builtin_amdgcn_exp2f)
  return __builtin_amdgcn_exp2f(v);
#else
  return exp2f(v);
#endif
}

// ---- ws layout (u32 words) ----
constexpr int kOffBits = 0;                  // bitsR [512*16] row-major bitmask
constexpr int kOffPerm = kOffBits + kN * 16; // permG [512] sorted_pos -> row
constexpr int kOffDeg  = kOffPerm + kN;      // degG  [512] sorted_pos -> degree
constexpr int kOffRPos = kOffDeg + kN;       // rowpos[512] row -> sorted_pos
constexpr int kOffIdx  = kOffRPos + kN;      // idxG  [kMaxDeg*512] slot-major

// Coalesced pack: bit jj of bitsR[i*16+w] = (adj[i][w*32+jj] != 0).
__global__ void pack_adj_kernel(const float* __restrict__ adj,
                                uint* __restrict__ bitsR) {
  const int t = blockIdx.x * blockDim.x + threadIdx.x;  // [0, 512*512)
  const unsigned long long m = __ballot(adj[t] != 0.0f);
  const int lane = threadIdx.x & 63;
  if ((lane & 31) == 0) {
    const int i = t >> 9;
    const int w = (t & 511) >> 5;
    bitsR[i * 16 + w] = (uint)(m >> (lane & 32));
  }
}

// One block, 512 threads: degree -> LDS counting sort by degree -> position
// assignment only (no heavy stores).
__global__ __launch_bounds__(512) void sort_assign_kernel(
    const uint* __restrict__ bitsR, uint* __restrict__ permG,
    uint* __restrict__ degG, uint* __restrict__ rowpos) {
  __shared__ int base[128];
  const int i = threadIdx.x;
  int deg = 0;
#pragma unroll
  for (int w = 0; w < 16; ++w) deg += __popc(bitsR[i * 16 + w]);
  const int dc = min(deg, 127);

  if (i < 128) base[i] = 0;
  __syncthreads();
  atomicAdd(&base[dc], 1);           // histogram
  __syncthreads();
  if (i == 0) {                      // exclusive prefix over 128 bins
    int run = 0;
    for (int k = 0; k < 128; ++k) {
      const int c = base[k];
      base[k] = run;
      run += c;
    }
  }
  __syncthreads();
  const int pos = atomicAdd(&base[dc], 1);  // allocation cursor within bin
  permG[pos] = (uint)i;
  degG[pos] = (uint)deg;
  rowpos[i] = (uint)pos;
}

// 512 blocks x 1 wave: row per block. Lanes 0..15 own one bitmask word each;
// wave prefix-popc gives each word's slot base; scatter indices slot-major.
__global__ __launch_bounds__(64) void csr_fill_kernel(
    const uint* __restrict__ bitsR, const uint* __restrict__ rowpos,
    uint* __restrict__ idxG) {
  const int i = blockIdx.x;
  const int l = threadIdx.x;
  const int pos = (int)rowpos[i];  // wave-uniform
  uint b = (l < 16) ? bitsR[i * 16 + l] : 0u;
  const int cnt = __popc(b);
  int scan = cnt;  // inclusive scan over lanes
#pragma unroll
  for (int off = 1; off < 16; off <<= 1) {
    const int v = __shfl_up(scan, off, 64);
    if (l >= off) scan += v;
  }
  int slot = scan - cnt;  // exclusive prefix
  while (b) {
    const int j = l * 32 + __builtin_ctz(b);
    b &= b - 1;
    idxG[slot * kN + pos] = (uint)j;
    ++slot;
  }
}

// One block per (bt, h); bt fast in blockIdx so all 8 heads of a bt share an
// XCD (L2 reuse of the x-tile). Phase 1: h-tile + logit vectors. Phase 2:
// sparse softmax+PV over sorted slot-major CSR.
__global__ __launch_bounds__(kNT) void gat_sparse_kernel(
    const float* __restrict__ x, const uint* __restrict__ permG,
    const uint* __restrict__ degG, const uint* __restrict__ idxG,
    const float* __restrict__ W, const float* __restrict__ Wb,
    const float* __restrict__ a1, const float* __restrict__ a2,
    const float* __restrict__ ab, float* __restrict__ out) {
  __shared__ _Float16 h16S[kN * 8];  // 8 KB f16 h rows
  __shared__ float ssrcS[kN];        // log2e * (a1.h_j)
  __shared__ float sdstS[kN];        // log2e * (a2.h_i + ab)

  const int bt  = blockIdx.x % kBT;
  const int h   = blockIdx.x / kBT;
  const int tid = threadIdx.x;

  const float* xb = x + (size_t)bt * kN * kFin;
  const float* Wl = W + h * kFin * kFp;  // wave-uniform -> s_loads

  // ---------------- Phase 1: h = x @ W_h + b_h (rows tid, tid+256) ----------
  float xr0[kFin], xr1[kFin];
  {
    const float4* p0 = reinterpret_cast<const float4*>(xb + (size_t)tid * kFin);
    const float4* p1 =
        reinterpret_cast<const float4*>(xb + (size_t)(tid + kNT) * kFin);
#pragma unroll
    for (int c4 = 0; c4 < kFin / 4; ++c4) {
      *reinterpret_cast<float4*>(&xr0[c4 * 4]) = p0[c4];
      *reinterpret_cast<float4*>(&xr1[c4 * 4]) = p1[c4];
    }
  }

  float acc0[kFp], acc1[kFp];
#pragma unroll
  for (int f = 0; f < kFp; ++f) {
    const float b = Wb[h * kFp + f];
    acc0[f] = b;
    acc1[f] = b;
  }
#pragma unroll
  for (int i = 0; i < kFin; ++i) {
#pragma unroll
    for (int f = 0; f < kFp; ++f) {
      const float wv = Wl[i * kFp + f];
      acc0[f] = fmaf(xr0[i], wv, acc0[f]);
      acc1[f] = fmaf(xr1[i], wv, acc1[f]);
    }
  }

  float s1a = 0.f, s2a = 0.f, s1b = 0.f, s2b = 0.f;
#pragma unroll
  for (int f = 0; f < kFp; ++f) {
    const float A1 = a1[h * kFp + f];
    const float A2 = a2[h * kFp + f];
    s1a = fmaf(acc0[f], A1, s1a);
    s2a = fmaf(acc0[f], A2, s2a);
    s1b = fmaf(acc1[f], A1, s1b);
    s2b = fmaf(acc1[f], A2, s2b);
  }
  const float abh = ab[h];
  ssrcS[tid]       = s1a * kL2E;
  ssrcS[tid + kNT] = s1b * kL2E;
  sdstS[tid]       = (s2a + abh) * kL2E;
  sdstS[tid + kNT] = (s2b + abh) * kL2E;

  {
    half8t hv;
#pragma unroll
    for (int f = 0; f < kFp; ++f) hv[f] = (_Float16)acc0[f];
    *reinterpret_cast<half8t*>(&h16S[(size_t)tid * 8]) = hv;
#pragma unroll
    for (int f = 0; f < kFp; ++f) hv[f] = (_Float16)acc1[f];
    *reinterpret_cast<half8t*>(&h16S[(size_t)(tid + kNT) * 8]) = hv;
  }
  __syncthreads();

  // ---------------- Phase 2: sparse masked softmax + PV ---------------------
  // Thread handles adjacent sorted positions 2t, 2t+1 (similar degree).
  const int p0 = 2 * tid;
  const uint2 ip = *reinterpret_cast<const uint2*>(&permG[p0]);
  const uint2 dp = *reinterpret_cast<const uint2*>(&degG[p0]);
  const int i0 = (int)ip.x, i1 = (int)ip.y;
  const int d0 = (int)dp.x, d1 = (int)dp.y;
  const float sd0 = sdstS[i0];
  const float sd1 = sdstS[i1];
  const int dmax = max(d0, d1);  // <= ~45 << kMaxDeg

  float o0[kFp], o1[kFp];
#pragma unroll
  for (int f = 0; f < kFp; ++f) {
    o0[f] = 0.f;
    o1[f] = 0.f;
  }
  float sum0 = 0.f, sum1 = 0.f;

  uint2 jj = *reinterpret_cast<const uint2*>(&idxG[p0]);  // slot 0 (deg >= 1)
#pragma unroll 1
  for (int slot = 0; slot < dmax; ++slot) {
    // Prefetch next slot; mem-safe (slot+1 < kMaxDeg), content may be pad
    // garbage -> clamped below, q predicated to 0.
    const uint2 jn =
        *reinterpret_cast<const uint2*>(&idxG[(slot + 1) * kN + p0]);
    const int j0 = (int)(jj.x & 511u);
    const int j1 = (int)(jj.y & 511u);

    const half8t hv0 = *reinterpret_cast<const half8t*>(&h16S[(size_t)j0 * 8]);
    const half8t hv1 = *reinterpret_cast<const half8t*>(&h16S[(size_t)j1 * 8]);
    float e0 = ssrcS[j0] + sd0;
    float e1 = ssrcS[j1] + sd1;
    e0 = fmaxf(e0, e0 * kNeg);  // leaky-relu (commutes with log2e scale)
    e1 = fmaxf(e1, e1 * kNeg);
    float q0 = fast_exp2(e0);
    float q1 = fast_exp2(e1);
    q0 = (slot < d0) ? q0 : 0.f;
    q1 = (slot < d1) ? q1 : 0.f;
    sum0 += q0;
    sum1 += q1;
#pragma unroll
    for (int f = 0; f < kFp; ++f) {
      o0[f] = fmaf((float)hv0[f], q0, o0[f]);  // v_fma_mix_f32
      o1[f] = fmaf((float)hv1[f], q1, o1[f]);
    }
    jj = jn;
  }

  // ---------------- Epilogue: normalize + head-concat store -----------------
  const float r0 = 1.0f / sum0;
  const float r1 = 1.0f / sum1;
  float* q0p = out + (((size_t)bt * kN + i0) * kH + h) * kFp;
  float* q1p = out + (((size_t)bt * kN + i1) * kH + h) * kFp;
  reinterpret_cast<float4*>(q0p)[0] =
      make_float4(o0[0] * r0, o0[1] * r0, o0[2] * r0, o0[3] * r0);
  reinterpret_cast<float4*>(q0p)[1] =
      make_float4(o0[4] * r0, o0[5] * r0, o0[6] * r0, o0[7] * r0);
  reinterpret_cast<float4*>(q1p)[0] =
      make_float4(o1[0] * r1, o1[1] * r1, o1[2] * r1, o1[3] * r1);
  reinterpret_cast<float4*>(q1p)[1] =
      make_float4(o1[4] * r1, o1[5] * r1, o1[6] * r1, o1[7] * r1);
}

}  // namespace

extern "C" void kernel_launch(void* const* d_in, const int* in_sizes, int n_in,
                              void* d_out, int out_size, void* d_ws, size_t ws_size,
                              hipStream_t stream) {
  const float* x   = (const float*)d_in[0];
  const float* adj = (const float*)d_in[1];
  const float* W   = (const float*)d_in[2];
  const float* Wb  = (const float*)d_in[3];
  const float* a1  = (const float*)d_in[4];
  const float* a2  = (const float*)d_in[5];
  const float* ab  = (const float*)d_in[6];
  float* out = (float*)d_out;

  uint* ws     = (uint*)d_ws;
  uint* bitsR  = ws + kOffBits;
  uint* permG  = ws + kOffPerm;
  uint* degG   = ws + kOffDeg;
  uint* rowpos = ws + kOffRPos;
  uint* idxG   = ws + kOffIdx;

  hipLaunchKernelGGL(pack_adj_kernel, dim3(kN * kN / kNT), dim3(kNT), 0, stream,
                     adj, bitsR);
  hipLaunchKernelGGL(sort_assign_kernel, dim3(1), dim3(512), 0, stream,
                     bitsR, permG, degG, rowpos);
  hipLaunchKernelGGL(csr_fill_kernel, dim3(kN), dim3(64), 0, stream,
                     bitsR, rowpos, idxG);
  hipLaunchKernelGGL(gat_sparse_kernel, dim3(kBT * kH), dim3(kNT), 0, stream,
                     x, permG, degG, idxG, W, Wb, a1, a2, ab, out);
}

// Round 9
// 103.459 us; speedup vs baseline: 1.6079x; 1.0412x over previous
//
#include <hip/hip_runtime.h>
#include <math.h>

namespace {

constexpr int kN    = 512;
constexpr int kFin  = 64;
constexpr int kH    = 8;
constexpr int kFp   = 8;
constexpr int kBT   = 96;
constexpr int kNT   = 256;
constexpr int kMaxDeg = 104;   // idxG slot capacity (max row degree ~45)
constexpr float kNeg = 0.01f;
constexpr float kL2E = 1.44269504088896340736f;  // log2(e)

typedef _Float16 half8t __attribute__((ext_vector_type(8)));
typedef unsigned int uint;

__device__ __forceinline__ float fast_exp2(float v) {
#if __has_builtin(__builtin_amdgcn_exp2f)
  return __builtin_amdgcn_exp2f(v);
#else
  return exp2f(v);
#endif
}

// ---- ws layout (u32 words) ----
constexpr int kOffBits = 0;                  // bitsR [512*16] row-major bitmask
constexpr int kOffPerm = kOffBits + kN * 16; // permG [512] sorted_pos -> row
constexpr int kOffDeg  = kOffPerm + kN;      // degG  [512] sorted_pos -> degree
constexpr int kOffIdx  = kOffDeg + kN;       // idxG  [kMaxDeg*512] slot-major

// Coalesced pack: bit jj of bitsR[i*16+w] = (adj[i][w*32+jj] != 0).
__global__ void pack_adj_kernel(const float* __restrict__ adj,
                                uint* __restrict__ bitsR) {
  const int t = blockIdx.x * blockDim.x + threadIdx.x;  // [0, 512*512)
  const unsigned long long m = __ballot(adj[t] != 0.0f);
  const int lane = threadIdx.x & 63;
  if ((lane & 31) == 0) {
    const int i = t >> 9;
    const int w = (t & 511) >> 5;
    bitsR[i * 16 + w] = (uint)(m >> (lane & 32));
  }
}

// 512 blocks x 1 wave; block i handles row i. Computes all 512 degrees from
// the bitmask (L2-hot), ranks row i by (deg, id) -- deterministic parallel
// replacement for the counting sort -- then scatters row i's column indices
// into slot-major padded CSR at column pos_i.
__global__ __launch_bounds__(64) void rank_fill_kernel(
    const uint* __restrict__ bitsR, uint* __restrict__ permG,
    uint* __restrict__ degG, uint* __restrict__ idxG) {
  __shared__ int degS[kN];
  const int i = blockIdx.x;
  const int l = threadIdx.x;

  // 1) all 512 degrees: lane l covers rows l, l+64, ..., l+448
#pragma unroll
  for (int r8 = 0; r8 < 8; ++r8) {
    const int r = l + r8 * 64;
    const uint4* p = reinterpret_cast<const uint4*>(&bitsR[r * 16]);
    const uint4 a = p[0], b = p[1], c = p[2], d = p[3];
    degS[r] = __popc(a.x) + __popc(a.y) + __popc(a.z) + __popc(a.w) +
              __popc(b.x) + __popc(b.y) + __popc(b.z) + __popc(b.w) +
              __popc(c.x) + __popc(c.y) + __popc(c.z) + __popc(c.w) +
              __popc(d.x) + __popc(d.y) + __popc(d.z) + __popc(d.w);
  }
  __syncthreads();

  // 2) rank of row i under lexicographic (deg, id)
  const int degi = degS[i];
  int cnt = 0;
#pragma unroll
  for (int r8 = 0; r8 < 8; ++r8) {
    const int r = l + r8 * 64;
    const int dr = degS[r];
    cnt += (dr < degi || (dr == degi && r < i)) ? 1 : 0;
  }
#pragma unroll
  for (int off = 32; off > 0; off >>= 1) cnt += __shfl_xor(cnt, off, 64);
  const int pos = cnt;  // wave-uniform
  if (l == 0) {
    permG[pos] = (uint)i;
    degG[pos] = (uint)degi;
  }

  // 3) CSR fill: lanes 0..15 own one bitmask word; prefix-popc -> slot base
  uint b = (l < 16) ? bitsR[i * 16 + l] : 0u;
  const int cntw = __popc(b);
  int scan = cntw;
#pragma unroll
  for (int off = 1; off < 16; off <<= 1) {
    const int v = __shfl_up(scan, off, 64);
    if (l >= off) scan += v;
  }
  int slot = scan - cntw;  // exclusive prefix
  while (b) {
    const int j = l * 32 + __builtin_ctz(b);
    b &= b - 1;
    idxG[slot * kN + pos] = (uint)j;
    ++slot;
  }
}

// One block per (bt, h); bt fast in blockIdx so all 8 heads of a bt share an
// XCD (L2 reuse of the x-tile). Phase 1: h-tile + logit vectors. Phase 2:
// sparse softmax+PV over sorted slot-major CSR.
__global__ __launch_bounds__(kNT) void gat_sparse_kernel(
    const float* __restrict__ x, const uint* __restrict__ permG,
    const uint* __restrict__ degG, const uint* __restrict__ idxG,
    const float* __restrict__ W, const float* __restrict__ Wb,
    const float* __restrict__ a1, const float* __restrict__ a2,
    const float* __restrict__ ab, float* __restrict__ out) {
  __shared__ _Float16 h16S[kN * 8];  // 8 KB f16 h rows
  __shared__ float ssrcS[kN];        // log2e * (a1.h_j)
  __shared__ float sdstS[kN];        // log2e * (a2.h_i + ab)

  const int bt  = blockIdx.x % kBT;
  const int h   = blockIdx.x / kBT;
  const int tid = threadIdx.x;

  // Hoist phase-2 index loads: latency hides under phase-1 FMAs.
  const int p0 = 2 * tid;
  const uint2 ip = *reinterpret_cast<const uint2*>(&permG[p0]);
  const uint2 dp = *reinterpret_cast<const uint2*>(&degG[p0]);
  uint2 jj = *reinterpret_cast<const uint2*>(&idxG[p0]);  // slot 0 (deg >= 1)

  const float* xb = x + (size_t)bt * kN * kFin;
  const float* Wl = W + h * kFin * kFp;  // wave-uniform -> s_loads

  // ---------------- Phase 1: h = x @ W_h + b_h (rows tid, tid+256) ----------
  float xr0[kFin], xr1[kFin];
  {
    const float4* px0 = reinterpret_cast<const float4*>(xb + (size_t)tid * kFin);
    const float4* px1 =
        reinterpret_cast<const float4*>(xb + (size_t)(tid + kNT) * kFin);
#pragma unroll
    for (int c4 = 0; c4 < kFin / 4; ++c4) {
      *reinterpret_cast<float4*>(&xr0[c4 * 4]) = px0[c4];
      *reinterpret_cast<float4*>(&xr1[c4 * 4]) = px1[c4];
    }
  }

  float acc0[kFp], acc1[kFp];
#pragma unroll
  for (int f = 0; f < kFp; ++f) {
    const float b = Wb[h * kFp + f];
    acc0[f] = b;
    acc1[f] = b;
  }
#pragma unroll
  for (int i = 0; i < kFin; ++i) {
#pragma unroll
    for (int f = 0; f < kFp; ++f) {
      const float wv = Wl[i * kFp + f];
      acc0[f] = fmaf(xr0[i], wv, acc0[f]);
      acc1[f] = fmaf(xr1[i], wv, acc1[f]);
    }
  }

  float s1a = 0.f, s2a = 0.f, s1b = 0.f, s2b = 0.f;
#pragma unroll
  for (int f = 0; f < kFp; ++f) {
    const float A1 = a1[h * kFp + f];
    const float A2 = a2[h * kFp + f];
    s1a = fmaf(acc0[f], A1, s1a);
    s2a = fmaf(acc0[f], A2, s2a);
    s1b = fmaf(acc1[f], A1, s1b);
    s2b = fmaf(acc1[f], A2, s2b);
  }
  const float abh = ab[h];
  ssrcS[tid]       = s1a * kL2E;
  ssrcS[tid + kNT] = s1b * kL2E;
  sdstS[tid]       = (s2a + abh) * kL2E;
  sdstS[tid + kNT] = (s2b + abh) * kL2E;

  {
    half8t hv;
#pragma unroll
    for (int f = 0; f < kFp; ++f) hv[f] = (_Float16)acc0[f];
    *reinterpret_cast<half8t*>(&h16S[(size_t)tid * 8]) = hv;
#pragma unroll
    for (int f = 0; f < kFp; ++f) hv[f] = (_Float16)acc1[f];
    *reinterpret_cast<half8t*>(&h16S[(size_t)(tid + kNT) * 8]) = hv;
  }
  __syncthreads();

  // ---------------- Phase 2: sparse masked softmax + PV ---------------------
  // Thread handles adjacent sorted positions 2t, 2t+1 (similar degree).
  const int i0 = (int)ip.x, i1 = (int)ip.y;
  const int d0 = (int)dp.x, d1 = (int)dp.y;
  const float sd0 = sdstS[i0];
  const float sd1 = sdstS[i1];
  const int dmax = max(d0, d1);  // <= ~45 << kMaxDeg

  float o0[kFp], o1[kFp];
#pragma unroll
  for (int f = 0; f < kFp; ++f) {
    o0[f] = 0.f;
    o1[f] = 0.f;
  }
  float sum0 = 0.f, sum1 = 0.f;

#pragma unroll 1
  for (int slot = 0; slot < dmax; ++slot) {
    // Prefetch next slot; mem-safe (slot+1 < kMaxDeg); content beyond a row's
    // degree is ws poison -> clamped below, q predicated to 0.
    const uint2 jn =
        *reinterpret_cast<const uint2*>(&idxG[(slot + 1) * kN + p0]);
    const int j0 = (int)(jj.x & 511u);
    const int j1 = (int)(jj.y & 511u);

    const half8t hv0 = *reinterpret_cast<const half8t*>(&h16S[(size_t)j0 * 8]);
    const half8t hv1 = *reinterpret_cast<const half8t*>(&h16S[(size_t)j1 * 8]);
    float e0 = ssrcS[j0] + sd0;
    float e1 = ssrcS[j1] + sd1;
    e0 = fmaxf(e0, e0 * kNeg);  // leaky-relu (commutes with log2e scale)
    e1 = fmaxf(e1, e1 * kNeg);
    float q0 = fast_exp2(e0);
    float q1 = fast_exp2(e1);
    q0 = (slot < d0) ? q0 : 0.f;
    q1 = (slot < d1) ? q1 : 0.f;
    sum0 += q0;
    sum1 += q1;
#pragma unroll
    for (int f = 0; f < kFp; ++f) {
      o0[f] = fmaf((float)hv0[f], q0, o0[f]);  // v_fma_mix_f32
      o1[f] = fmaf((float)hv1[f], q1, o1[f]);
    }
    jj = jn;
  }

  // ---------------- Epilogue: normalize + head-concat store -----------------
  const float r0 = 1.0f / sum0;
  const float r1 = 1.0f / sum1;
  float* q0p = out + (((size_t)bt * kN + i0) * kH + h) * kFp;
  float* q1p = out + (((size_t)bt * kN + i1) * kH + h) * kFp;
  reinterpret_cast<float4*>(q0p)[0] =
      make_float4(o0[0] * r0, o0[1] * r0, o0[2] * r0, o0[3] * r0);
  reinterpret_cast<float4*>(q0p)[1] =
      make_float4(o0[4] * r0, o0[5] * r0, o0[6] * r0, o0[7] * r0);
  reinterpret_cast<float4*>(q1p)[0] =
      make_float4(o1[0] * r1, o1[1] * r1, o1[2] * r1, o1[3] * r1);
  reinterpret_cast<float4*>(q1p)[1] =
      make_float4(o1[4] * r1, o1[5] * r1, o1[6] * r1, o1[7] * r1);
}

}  // namespace

extern "C" void kernel_launch(void* const* d_in, const int* in_sizes, int n_in,
                              void* d_out, int out_size, void* d_ws, size_t ws_size,
                              hipStream_t stream) {
  const float* x   = (const float*)d_in[0];
  const float* adj = (const float*)d_in[1];
  const float* W   = (const float*)d_in[2];
  const float* Wb  = (const float*)d_in[3];
  const float* a1  = (const float*)d_in[4];
  const float* a2  = (const float*)d_in[5];
  const float* ab  = (const float*)d_in[6];
  float* out = (float*)d_out;

  uint* ws    = (uint*)d_ws;
  uint* bitsR = ws + kOffBits;
  uint* permG = ws + kOffPerm;
  uint* degG  = ws + kOffDeg;
  uint* idxG  = ws + kOffIdx;

  hipLaunchKernelGGL(pack_adj_kernel, dim3(kN * kN / kNT), dim3(kNT), 0, stream,
                     adj, bitsR);
  hipLaunchKernelGGL(rank_fill_kernel, dim3(kN), dim3(64), 0, stream,
                     bitsR, permG, degG, idxG);
  hipLaunchKernelGGL(gat_sparse_kernel, dim3(kBT * kH), dim3(kNT), 0, stream,
                     x, permG, degG, idxG, W, Wb, a1, a2, ab, out);
}